// Round 10
// baseline (515.385 us; speedup 1.0000x reference)
//
#include <hip/hip_runtime.h>

#define NPIX  (1024 * 1024)
#define NVEC  (NPIX / 4)
#define NSTAT 21
#define RBLOCKS  128   // partial blocks per batch (must equal solve block size)
#define RTHREADS 256
// NVEC / (RBLOCKS*RTHREADS) == 8 iterations exactly
#define RITERS (NVEC / (RBLOCKS * RTHREADS))
#define RSTRIDE (RBLOCKS * RTHREADS)

// ---------------------------------------------------------------------------
// Pass 1: per-batch raw sums. fp32 per-thread accumulators (32 px/thread),
// fp64 from the wave reduction onward. Depth-2 software pipeline over three
// NAMED register slot-sets (x/y/z) so slot indices are compile-time and the
// compiler's use-driven vmcnt keeps 12 loads in flight per wave.
// __launch_bounds__(256,2) gives the register allocator headroom (~110 VGPR)
// instead of clamping to 64 and serializing the loads (round-5 lesson).
// NOTE: (s##0).x parens are required — "s##0.x" pastes with pp-number "0.x".
// stats: 0-2 sumA_c, 3-5 sumB_c, 6-11 sym sumA_i*A_j (00,01,02,11,12,22),
//        12-20 sumB_i*A_j row-major.
// partials layout: [batch][stat][RBLOCKS] doubles (fully rewritten each call).
// ---------------------------------------------------------------------------
__global__ __launch_bounds__(RTHREADS, 2) void reduce_stats(
    const float4* __restrict__ src, const float4* __restrict__ dst,
    double* __restrict__ partials)
{
    const int b  = blockIdx.y;
    const int pb = blockIdx.x;

    const float4* A0 = src + (size_t)b * 3 * NVEC;
    const float4* A1 = A0 + NVEC;
    const float4* A2 = A0 + 2 * NVEC;
    const float4* B0 = dst + (size_t)b * 3 * NVEC;
    const float4* B1 = B0 + NVEC;
    const float4* B2 = B0 + 2 * NVEC;

    float acc[NSTAT];
#pragma unroll
    for (int s = 0; s < NSTAT; ++s) acc[s] = 0.0f;

#define ACC1(A0v, A1v, A2v, B0v, B1v, B2v)                                   \
    do {                                                                     \
        acc[0] += (A0v); acc[1] += (A1v); acc[2] += (A2v);                   \
        acc[3] += (B0v); acc[4] += (B1v); acc[5] += (B2v);                   \
        acc[6]  = fmaf((A0v), (A0v), acc[6]);                                \
        acc[7]  = fmaf((A0v), (A1v), acc[7]);                                \
        acc[8]  = fmaf((A0v), (A2v), acc[8]);                                \
        acc[9]  = fmaf((A1v), (A1v), acc[9]);                                \
        acc[10] = fmaf((A1v), (A2v), acc[10]);                               \
        acc[11] = fmaf((A2v), (A2v), acc[11]);                               \
        acc[12] = fmaf((B0v), (A0v), acc[12]);                               \
        acc[13] = fmaf((B0v), (A1v), acc[13]);                               \
        acc[14] = fmaf((B0v), (A2v), acc[14]);                               \
        acc[15] = fmaf((B1v), (A0v), acc[15]);                               \
        acc[16] = fmaf((B1v), (A1v), acc[16]);                               \
        acc[17] = fmaf((B1v), (A2v), acc[17]);                               \
        acc[18] = fmaf((B2v), (A0v), acc[18]);                               \
        acc[19] = fmaf((B2v), (A1v), acc[19]);                               \
        acc[20] = fmaf((B2v), (A2v), acc[20]);                               \
    } while (0)

    // slot = 6 named float4 regs; LOADS issues 6 loads, ACCS consumes them.
#define LOADS(s, k)                                                          \
    do {                                                                     \
        const int pp = p0 + (k) * RSTRIDE;                                   \
        s##0 = A0[pp]; s##1 = A1[pp]; s##2 = A2[pp];                         \
        s##3 = B0[pp]; s##4 = B1[pp]; s##5 = B2[pp];                         \
    } while (0)

#define ACCS(s)                                                              \
    do {                                                                     \
        ACC1((s##0).x, (s##1).x, (s##2).x, (s##3).x, (s##4).x, (s##5).x);    \
        ACC1((s##0).y, (s##1).y, (s##2).y, (s##3).y, (s##4).y, (s##5).y);    \
        ACC1((s##0).z, (s##1).z, (s##2).z, (s##3).z, (s##4).z, (s##5).z);    \
        ACC1((s##0).w, (s##1).w, (s##2).w, (s##3).w, (s##4).w, (s##5).w);    \
    } while (0)

    const int p0 = pb * RTHREADS + threadIdx.x;

    float4 x0, x1, x2, x3, x4, x5;
    float4 y0, y1, y2, y3, y4, y5;
    float4 z0, z1, z2, z3, z4, z5;

    // RITERS == 8; rotation x,y,z,x,y,z,x,y; prefetch 2 ahead.
    LOADS(x, 0);
    LOADS(y, 1);
    LOADS(z, 2);  ACCS(x);
    LOADS(x, 3);  ACCS(y);
    LOADS(y, 4);  ACCS(z);
    LOADS(z, 5);  ACCS(x);
    LOADS(x, 6);  ACCS(y);
    LOADS(y, 7);  ACCS(z);
                  ACCS(x);
                  ACCS(y);
#undef LOADS
#undef ACCS
#undef ACC1

    // wave (64-lane) butterfly reduce each stat in fp64
    double accd[NSTAT];
#pragma unroll
    for (int s = 0; s < NSTAT; ++s) {
        double v = (double)acc[s];
        for (int off = 32; off > 0; off >>= 1) v += __shfl_down(v, off, 64);
        accd[s] = v;
    }

    __shared__ double part[RTHREADS / 64][NSTAT];
    const int lane = threadIdx.x & 63;
    const int wid  = threadIdx.x >> 6;
    if (lane == 0) {
#pragma unroll
        for (int s = 0; s < NSTAT; ++s) part[wid][s] = accd[s];
    }
    __syncthreads();

    if (threadIdx.x < NSTAT) {
        const int s = threadIdx.x;
        double v = part[0][s] + part[1][s] + part[2][s] + part[3][s];
        partials[((size_t)b * NSTAT + s) * RBLOCKS + pb] = v;
    }
}

// ---------------------------------------------------------------------------
// Pass 2: reduce partials + 3x3 solve per batch. coef[b][12] fp32:
//   0..8 = x row-major, 9..11 = offset_c = bm_c - sum_j x[c][j]*am_j
// ---------------------------------------------------------------------------
__global__ __launch_bounds__(RBLOCKS) void solve3x3(
    const double* __restrict__ partials, float* __restrict__ coef)
{
    const int b = blockIdx.x;
    const int t = threadIdx.x;  // RBLOCKS threads, 2 waves

    __shared__ double wsum[NSTAT][2];

#pragma unroll
    for (int s = 0; s < NSTAT; ++s) {
        double v = partials[((size_t)b * NSTAT + s) * RBLOCKS + t];
        for (int off = 32; off > 0; off >>= 1) v += __shfl_down(v, off, 64);
        if ((t & 63) == 0) wsum[s][t >> 6] = v;
    }
    __syncthreads();

    if (t == 0) {
        double st[NSTAT];
#pragma unroll
        for (int s = 0; s < NSTAT; ++s) st[s] = wsum[s][0] + wsum[s][1];

        const double N = (double)NPIX;
        double am[3] = {st[0] / N, st[1] / N, st[2] / N};
        double bm[3] = {st[3] / N, st[4] / N, st[5] / N};

        double AA[3][3];
        AA[0][0] = st[6]  - N * am[0] * am[0] + 0.001;
        AA[0][1] = st[7]  - N * am[0] * am[1];
        AA[0][2] = st[8]  - N * am[0] * am[2];
        AA[1][1] = st[9]  - N * am[1] * am[1] + 0.001;
        AA[1][2] = st[10] - N * am[1] * am[2];
        AA[2][2] = st[11] - N * am[2] * am[2] + 0.001;
        AA[1][0] = AA[0][1]; AA[2][0] = AA[0][2]; AA[2][1] = AA[1][2];

        double BA[3][3];
#pragma unroll
        for (int i = 0; i < 3; ++i)
#pragma unroll
            for (int j = 0; j < 3; ++j)
                BA[i][j] = st[12 + 3 * i + j] - N * bm[i] * am[j];

        // 3x3 inverse via adjugate
        double c00 =  AA[1][1] * AA[2][2] - AA[1][2] * AA[2][1];
        double c01 = -(AA[1][0] * AA[2][2] - AA[1][2] * AA[2][0]);
        double c02 =  AA[1][0] * AA[2][1] - AA[1][1] * AA[2][0];
        double det = AA[0][0] * c00 + AA[0][1] * c01 + AA[0][2] * c02;
        double id  = 1.0 / det;

        double inv[3][3];
        inv[0][0] = c00 * id;
        inv[1][0] = c01 * id;
        inv[2][0] = c02 * id;
        inv[0][1] = -(AA[0][1] * AA[2][2] - AA[0][2] * AA[2][1]) * id;
        inv[1][1] =  (AA[0][0] * AA[2][2] - AA[0][2] * AA[2][0]) * id;
        inv[2][1] = -(AA[0][0] * AA[2][1] - AA[0][1] * AA[2][0]) * id;
        inv[0][2] =  (AA[0][1] * AA[1][2] - AA[0][2] * AA[1][1]) * id;
        inv[1][2] = -(AA[0][0] * AA[1][2] - AA[0][2] * AA[1][0]) * id;
        inv[2][2] =  (AA[0][0] * AA[1][1] - AA[0][1] * AA[1][0]) * id;

        double X[3][3];
#pragma unroll
        for (int i = 0; i < 3; ++i)
#pragma unroll
            for (int j = 0; j < 3; ++j)
                X[i][j] = BA[i][0] * inv[0][j] + BA[i][1] * inv[1][j] +
                          BA[i][2] * inv[2][j];

        float* cb = coef + b * 12;
#pragma unroll
        for (int i = 0; i < 3; ++i) {
#pragma unroll
            for (int j = 0; j < 3; ++j) cb[3 * i + j] = (float)X[i][j];
            cb[9 + i] = (float)(bm[i] - (X[i][0] * am[0] + X[i][1] * am[1] +
                                         X[i][2] * am[2]));
        }
    }
}

// ---------------------------------------------------------------------------
// Pass 3: out[b][c][n] = sum_j x[c][j]*src[b][j][n] + offset[c]
// Depth-2 named-slot pipeline like pass 1 (3 streams -> 9 float4 in flight).
// ---------------------------------------------------------------------------
__global__ __launch_bounds__(256, 2) void apply_map(
    const float4* __restrict__ src, float4* __restrict__ out,
    const float* __restrict__ coef)
{
    const int b = blockIdx.y;
    const float* cb = coef + b * 12;
    const float x00 = cb[0], x01 = cb[1], x02 = cb[2];
    const float x10 = cb[3], x11 = cb[4], x12 = cb[5];
    const float x20 = cb[6], x21 = cb[7], x22 = cb[8];
    const float o0 = cb[9], o1 = cb[10], o2 = cb[11];

    const float4* A0 = src + (size_t)b * 3 * NVEC;
    const float4* A1 = A0 + NVEC;
    const float4* A2 = A0 + 2 * NVEC;
    float4* O0 = out + (size_t)b * 3 * NVEC;
    float4* O1 = O0 + NVEC;
    float4* O2 = O0 + 2 * NVEC;

    const int p0 = blockIdx.x * 256 + threadIdx.x;

#define ALOAD(s, k)                                                          \
    do {                                                                     \
        const int pp = p0 + (k) * RSTRIDE;                                   \
        s##0 = A0[pp]; s##1 = A1[pp]; s##2 = A2[pp];                         \
    } while (0)

#define ASTORE(s, k)                                                         \
    do {                                                                     \
        const int pp = p0 + (k) * RSTRIDE;                                   \
        float4 r0, r1, r2;                                                   \
        r0.x = fmaf(x00, (s##0).x, fmaf(x01, (s##1).x, fmaf(x02, (s##2).x, o0))); \
        r1.x = fmaf(x10, (s##0).x, fmaf(x11, (s##1).x, fmaf(x12, (s##2).x, o1))); \
        r2.x = fmaf(x20, (s##0).x, fmaf(x21, (s##1).x, fmaf(x22, (s##2).x, o2))); \
        r0.y = fmaf(x00, (s##0).y, fmaf(x01, (s##1).y, fmaf(x02, (s##2).y, o0))); \
        r1.y = fmaf(x10, (s##0).y, fmaf(x11, (s##1).y, fmaf(x12, (s##2).y, o1))); \
        r2.y = fmaf(x20, (s##0).y, fmaf(x21, (s##1).y, fmaf(x22, (s##2).y, o2))); \
        r0.z = fmaf(x00, (s##0).z, fmaf(x01, (s##1).z, fmaf(x02, (s##2).z, o0))); \
        r1.z = fmaf(x10, (s##0).z, fmaf(x11, (s##1).z, fmaf(x12, (s##2).z, o1))); \
        r2.z = fmaf(x20, (s##0).z, fmaf(x21, (s##1).z, fmaf(x22, (s##2).z, o2))); \
        r0.w = fmaf(x00, (s##0).w, fmaf(x01, (s##1).w, fmaf(x02, (s##2).w, o0))); \
        r1.w = fmaf(x10, (s##0).w, fmaf(x11, (s##1).w, fmaf(x12, (s##2).w, o1))); \
        r2.w = fmaf(x20, (s##0).w, fmaf(x21, (s##1).w, fmaf(x22, (s##2).w, o2))); \
        O0[pp] = r0; O1[pp] = r1; O2[pp] = r2;                               \
    } while (0)

    float4 u0, u1, u2;
    float4 v0, v1, v2;
    float4 w0, w1, w2;

    // RITERS == 8; rotation u,v,w,u,v,w,u,v; prefetch 2 ahead.
    ALOAD(u, 0);
    ALOAD(v, 1);
    ALOAD(w, 2);  ASTORE(u, 0);
    ALOAD(u, 3);  ASTORE(v, 1);
    ALOAD(v, 4);  ASTORE(w, 2);
    ALOAD(w, 5);  ASTORE(u, 3);
    ALOAD(u, 6);  ASTORE(v, 4);
    ALOAD(v, 7);  ASTORE(w, 5);
                  ASTORE(u, 6);
                  ASTORE(v, 7);
#undef ALOAD
#undef ASTORE
}

extern "C" void kernel_launch(void* const* d_in, const int* in_sizes, int n_in,
                              void* d_out, int out_size, void* d_ws, size_t ws_size,
                              hipStream_t stream)
{
    const float4* src = (const float4*)d_in[0];
    const float4* dst = (const float4*)d_in[1];
    float4* out = (float4*)d_out;

    const int batches = in_sizes[0] / (3 * NPIX);  // 16

    double* partials = (double*)d_ws;
    float*  coef = (float*)((char*)d_ws +
                            (size_t)batches * NSTAT * RBLOCKS * sizeof(double));

    reduce_stats<<<dim3(RBLOCKS, batches), RTHREADS, 0, stream>>>(src, dst, partials);
    solve3x3<<<batches, RBLOCKS, 0, stream>>>(partials, (float*)coef);
    apply_map<<<dim3(RBLOCKS, batches), 256, 0, stream>>>(src, out, coef);
}

// Round 11
// 506.771 us; speedup vs baseline: 1.0170x; 1.0170x over previous
//
#include <hip/hip_runtime.h>

#define NPIX  (1024 * 1024)
#define NVEC  (NPIX / 4)
#define NSTAT 21
#define RBLOCKS  128   // partial blocks per batch (must equal solve block size)
#define RTHREADS 256
// NVEC / (RBLOCKS*RTHREADS) == 8 iterations exactly
#define RITERS (NVEC / (RBLOCKS * RTHREADS))
#define RSTRIDE (RBLOCKS * RTHREADS)

// ---------------------------------------------------------------------------
// Pass 1: per-batch raw sums. fp32 per-thread accumulators (32 px/thread),
// fp64 from the wave reduction onward.
// Round-10 lesson: hipcc re-serializes C++-level prefetch (VGPR fell to 44).
// So the loads are inline-asm global_load_dwordx4 with hand-counted
// s_waitcnt vmcnt(N): 12 loads (12 KB) in flight per wave, guaranteed in the
// emitted ISA. sched_barrier(0) after each wait keeps register-only FMAs
// from hoisting past the wait (T18). No other vmem may appear in the loop
// (would corrupt the vmcnt count): all ACC is register FMA, no spills at
// ~110 VGPR with __launch_bounds__(256,2).
// vmcnt ledger (6 loads per ISSUE): issue0,issue1 -> 12 pending;
//   each [wait 6 -> oldest 6 done; issue next 6 -> back to 12; consume];
//   tail: wait 6 (iter6), wait 0 (iter7).
// stats: 0-2 sumA_c, 3-5 sumB_c, 6-11 sym sumA_i*A_j (00,01,02,11,12,22),
//        12-20 sumB_i*A_j row-major.
// partials layout: [batch][stat][RBLOCKS] doubles (fully rewritten each call).
// ---------------------------------------------------------------------------
__global__ __launch_bounds__(RTHREADS, 2) void reduce_stats(
    const float4* __restrict__ src, const float4* __restrict__ dst,
    double* __restrict__ partials)
{
    const int b  = blockIdx.y;
    const int pb = blockIdx.x;

    const float4* A0 = src + (size_t)b * 3 * NVEC;
    const float4* A1 = A0 + NVEC;
    const float4* A2 = A0 + 2 * NVEC;
    const float4* B0 = dst + (size_t)b * 3 * NVEC;
    const float4* B1 = B0 + NVEC;
    const float4* B2 = B0 + 2 * NVEC;

    float acc[NSTAT];
#pragma unroll
    for (int s = 0; s < NSTAT; ++s) acc[s] = 0.0f;

#define ACC1(A0v, A1v, A2v, B0v, B1v, B2v)                                   \
    do {                                                                     \
        acc[0] += (A0v); acc[1] += (A1v); acc[2] += (A2v);                   \
        acc[3] += (B0v); acc[4] += (B1v); acc[5] += (B2v);                   \
        acc[6]  = fmaf((A0v), (A0v), acc[6]);                                \
        acc[7]  = fmaf((A0v), (A1v), acc[7]);                                \
        acc[8]  = fmaf((A0v), (A2v), acc[8]);                                \
        acc[9]  = fmaf((A1v), (A1v), acc[9]);                                \
        acc[10] = fmaf((A1v), (A2v), acc[10]);                               \
        acc[11] = fmaf((A2v), (A2v), acc[11]);                               \
        acc[12] = fmaf((B0v), (A0v), acc[12]);                               \
        acc[13] = fmaf((B0v), (A1v), acc[13]);                               \
        acc[14] = fmaf((B0v), (A2v), acc[14]);                               \
        acc[15] = fmaf((B1v), (A0v), acc[15]);                               \
        acc[16] = fmaf((B1v), (A1v), acc[16]);                               \
        acc[17] = fmaf((B1v), (A2v), acc[17]);                               \
        acc[18] = fmaf((B2v), (A0v), acc[18]);                               \
        acc[19] = fmaf((B2v), (A1v), acc[19]);                               \
        acc[20] = fmaf((B2v), (A2v), acc[20]);                               \
    } while (0)

    // 6 asm loads per iteration into one named slot-set. asm volatile keeps
    // issue order; outputs are 128-bit VGPR quads the compiler cannot sink.
#define GLD(dstv, p) \
    asm volatile("global_load_dwordx4 %0, %1, off" : "=v"(dstv) : "v"(p) : "memory")

#define ISSUE(s, k)                                                          \
    do {                                                                     \
        const int pp = p0 + (k) * RSTRIDE;                                   \
        GLD(s##0, A0 + pp); GLD(s##1, A1 + pp); GLD(s##2, A2 + pp);          \
        GLD(s##3, B0 + pp); GLD(s##4, B1 + pp); GLD(s##5, B2 + pp);          \
    } while (0)

#define WAIT6() do {                                                         \
        asm volatile("s_waitcnt vmcnt(6)" ::: "memory");                     \
        __builtin_amdgcn_sched_barrier(0); } while (0)
#define WAIT0() do {                                                         \
        asm volatile("s_waitcnt vmcnt(0)" ::: "memory");                     \
        __builtin_amdgcn_sched_barrier(0); } while (0)

#define ACCS(s)                                                              \
    do {                                                                     \
        ACC1((s##0).x, (s##1).x, (s##2).x, (s##3).x, (s##4).x, (s##5).x);    \
        ACC1((s##0).y, (s##1).y, (s##2).y, (s##3).y, (s##4).y, (s##5).y);    \
        ACC1((s##0).z, (s##1).z, (s##2).z, (s##3).z, (s##4).z, (s##5).z);    \
        ACC1((s##0).w, (s##1).w, (s##2).w, (s##3).w, (s##4).w, (s##5).w);    \
    } while (0)

    const int p0 = pb * RTHREADS + threadIdx.x;

    float4 x0, x1, x2, x3, x4, x5;
    float4 y0, y1, y2, y3, y4, y5;
    float4 z0, z1, z2, z3, z4, z5;

    // RITERS == 8; rotation x,y,z,...; 12 loads outstanding in steady state.
    ISSUE(x, 0);
    ISSUE(y, 1);
    WAIT6(); ISSUE(z, 2); ACCS(x);
    WAIT6(); ISSUE(x, 3); ACCS(y);
    WAIT6(); ISSUE(y, 4); ACCS(z);
    WAIT6(); ISSUE(z, 5); ACCS(x);
    WAIT6(); ISSUE(x, 6); ACCS(y);
    WAIT6(); ISSUE(y, 7); ACCS(z);
    WAIT6();              ACCS(x);
    WAIT0();              ACCS(y);
#undef ISSUE
#undef GLD
#undef WAIT6
#undef WAIT0
#undef ACCS
#undef ACC1

    // wave (64-lane) butterfly reduce each stat in fp64
    double accd[NSTAT];
#pragma unroll
    for (int s = 0; s < NSTAT; ++s) {
        double v = (double)acc[s];
        for (int off = 32; off > 0; off >>= 1) v += __shfl_down(v, off, 64);
        accd[s] = v;
    }

    __shared__ double part[RTHREADS / 64][NSTAT];
    const int lane = threadIdx.x & 63;
    const int wid  = threadIdx.x >> 6;
    if (lane == 0) {
#pragma unroll
        for (int s = 0; s < NSTAT; ++s) part[wid][s] = accd[s];
    }
    __syncthreads();

    if (threadIdx.x < NSTAT) {
        const int s = threadIdx.x;
        double v = part[0][s] + part[1][s] + part[2][s] + part[3][s];
        partials[((size_t)b * NSTAT + s) * RBLOCKS + pb] = v;
    }
}

// ---------------------------------------------------------------------------
// Pass 2: reduce partials + 3x3 solve per batch. coef[b][12] fp32:
//   0..8 = x row-major, 9..11 = offset_c = bm_c - sum_j x[c][j]*am_j
// ---------------------------------------------------------------------------
__global__ __launch_bounds__(RBLOCKS) void solve3x3(
    const double* __restrict__ partials, float* __restrict__ coef)
{
    const int b = blockIdx.x;
    const int t = threadIdx.x;  // RBLOCKS threads, 2 waves

    __shared__ double wsum[NSTAT][2];

#pragma unroll
    for (int s = 0; s < NSTAT; ++s) {
        double v = partials[((size_t)b * NSTAT + s) * RBLOCKS + t];
        for (int off = 32; off > 0; off >>= 1) v += __shfl_down(v, off, 64);
        if ((t & 63) == 0) wsum[s][t >> 6] = v;
    }
    __syncthreads();

    if (t == 0) {
        double st[NSTAT];
#pragma unroll
        for (int s = 0; s < NSTAT; ++s) st[s] = wsum[s][0] + wsum[s][1];

        const double N = (double)NPIX;
        double am[3] = {st[0] / N, st[1] / N, st[2] / N};
        double bm[3] = {st[3] / N, st[4] / N, st[5] / N};

        double AA[3][3];
        AA[0][0] = st[6]  - N * am[0] * am[0] + 0.001;
        AA[0][1] = st[7]  - N * am[0] * am[1];
        AA[0][2] = st[8]  - N * am[0] * am[2];
        AA[1][1] = st[9]  - N * am[1] * am[1] + 0.001;
        AA[1][2] = st[10] - N * am[1] * am[2];
        AA[2][2] = st[11] - N * am[2] * am[2] + 0.001;
        AA[1][0] = AA[0][1]; AA[2][0] = AA[0][2]; AA[2][1] = AA[1][2];

        double BA[3][3];
#pragma unroll
        for (int i = 0; i < 3; ++i)
#pragma unroll
            for (int j = 0; j < 3; ++j)
                BA[i][j] = st[12 + 3 * i + j] - N * bm[i] * am[j];

        // 3x3 inverse via adjugate
        double c00 =  AA[1][1] * AA[2][2] - AA[1][2] * AA[2][1];
        double c01 = -(AA[1][0] * AA[2][2] - AA[1][2] * AA[2][0]);
        double c02 =  AA[1][0] * AA[2][1] - AA[1][1] * AA[2][0];
        double det = AA[0][0] * c00 + AA[0][1] * c01 + AA[0][2] * c02;
        double id  = 1.0 / det;

        double inv[3][3];
        inv[0][0] = c00 * id;
        inv[1][0] = c01 * id;
        inv[2][0] = c02 * id;
        inv[0][1] = -(AA[0][1] * AA[2][2] - AA[0][2] * AA[2][1]) * id;
        inv[1][1] =  (AA[0][0] * AA[2][2] - AA[0][2] * AA[2][0]) * id;
        inv[2][1] = -(AA[0][0] * AA[2][1] - AA[0][1] * AA[2][0]) * id;
        inv[0][2] =  (AA[0][1] * AA[1][2] - AA[0][2] * AA[1][1]) * id;
        inv[1][2] = -(AA[0][0] * AA[1][2] - AA[0][2] * AA[1][0]) * id;
        inv[2][2] =  (AA[0][0] * AA[1][1] - AA[0][1] * AA[1][0]) * id;

        double X[3][3];
#pragma unroll
        for (int i = 0; i < 3; ++i)
#pragma unroll
            for (int j = 0; j < 3; ++j)
                X[i][j] = BA[i][0] * inv[0][j] + BA[i][1] * inv[1][j] +
                          BA[i][2] * inv[2][j];

        float* cb = coef + b * 12;
#pragma unroll
        for (int i = 0; i < 3; ++i) {
#pragma unroll
            for (int j = 0; j < 3; ++j) cb[3 * i + j] = (float)X[i][j];
            cb[9 + i] = (float)(bm[i] - (X[i][0] * am[0] + X[i][1] * am[1] +
                                         X[i][2] * am[2]));
        }
    }
}

// ---------------------------------------------------------------------------
// Pass 3: out[b][c][n] = sum_j x[c][j]*src[b][j][n] + offset[c]
// Unchanged from round 10 (passing); will inherit the asm-load treatment
// next round once reduce_stats confirms the mechanism.
// ---------------------------------------------------------------------------
__global__ __launch_bounds__(256, 2) void apply_map(
    const float4* __restrict__ src, float4* __restrict__ out,
    const float* __restrict__ coef)
{
    const int b = blockIdx.y;
    const float* cb = coef + b * 12;
    const float x00 = cb[0], x01 = cb[1], x02 = cb[2];
    const float x10 = cb[3], x11 = cb[4], x12 = cb[5];
    const float x20 = cb[6], x21 = cb[7], x22 = cb[8];
    const float o0 = cb[9], o1 = cb[10], o2 = cb[11];

    const float4* A0 = src + (size_t)b * 3 * NVEC;
    const float4* A1 = A0 + NVEC;
    const float4* A2 = A0 + 2 * NVEC;
    float4* O0 = out + (size_t)b * 3 * NVEC;
    float4* O1 = O0 + NVEC;
    float4* O2 = O0 + 2 * NVEC;

    const int p0 = blockIdx.x * 256 + threadIdx.x;

#define ALOAD(s, k)                                                          \
    do {                                                                     \
        const int pp = p0 + (k) * RSTRIDE;                                   \
        s##0 = A0[pp]; s##1 = A1[pp]; s##2 = A2[pp];                         \
    } while (0)

#define ASTORE(s, k)                                                         \
    do {                                                                     \
        const int pp = p0 + (k) * RSTRIDE;                                   \
        float4 r0, r1, r2;                                                   \
        r0.x = fmaf(x00, (s##0).x, fmaf(x01, (s##1).x, fmaf(x02, (s##2).x, o0))); \
        r1.x = fmaf(x10, (s##0).x, fmaf(x11, (s##1).x, fmaf(x12, (s##2).x, o1))); \
        r2.x = fmaf(x20, (s##0).x, fmaf(x21, (s##1).x, fmaf(x22, (s##2).x, o2))); \
        r0.y = fmaf(x00, (s##0).y, fmaf(x01, (s##1).y, fmaf(x02, (s##2).y, o0))); \
        r1.y = fmaf(x10, (s##0).y, fmaf(x11, (s##1).y, fmaf(x12, (s##2).y, o1))); \
        r2.y = fmaf(x20, (s##0).y, fmaf(x21, (s##1).y, fmaf(x22, (s##2).y, o2))); \
        r0.z = fmaf(x00, (s##0).z, fmaf(x01, (s##1).z, fmaf(x02, (s##2).z, o0))); \
        r1.z = fmaf(x10, (s##0).z, fmaf(x11, (s##1).z, fmaf(x12, (s##2).z, o1))); \
        r2.z = fmaf(x20, (s##0).z, fmaf(x21, (s##1).z, fmaf(x22, (s##2).z, o2))); \
        r0.w = fmaf(x00, (s##0).w, fmaf(x01, (s##1).w, fmaf(x02, (s##2).w, o0))); \
        r1.w = fmaf(x10, (s##0).w, fmaf(x11, (s##1).w, fmaf(x12, (s##2).w, o1))); \
        r2.w = fmaf(x20, (s##0).w, fmaf(x21, (s##1).w, fmaf(x22, (s##2).w, o2))); \
        O0[pp] = r0; O1[pp] = r1; O2[pp] = r2;                               \
    } while (0)

    float4 u0, u1, u2;
    float4 v0, v1, v2;
    float4 w0, w1, w2;

    // RITERS == 8; rotation u,v,w,u,v,w,u,v; prefetch 2 ahead.
    ALOAD(u, 0);
    ALOAD(v, 1);
    ALOAD(w, 2);  ASTORE(u, 0);
    ALOAD(u, 3);  ASTORE(v, 1);
    ALOAD(v, 4);  ASTORE(w, 2);
    ALOAD(w, 5);  ASTORE(u, 3);
    ALOAD(u, 6);  ASTORE(v, 4);
    ALOAD(v, 7);  ASTORE(w, 5);
                  ASTORE(u, 6);
                  ASTORE(v, 7);
#undef ALOAD
#undef ASTORE
}

extern "C" void kernel_launch(void* const* d_in, const int* in_sizes, int n_in,
                              void* d_out, int out_size, void* d_ws, size_t ws_size,
                              hipStream_t stream)
{
    const float4* src = (const float4*)d_in[0];
    const float4* dst = (const float4*)d_in[1];
    float4* out = (float4*)d_out;

    const int batches = in_sizes[0] / (3 * NPIX);  // 16

    double* partials = (double*)d_ws;
    float*  coef = (float*)((char*)d_ws +
                            (size_t)batches * NSTAT * RBLOCKS * sizeof(double));

    reduce_stats<<<dim3(RBLOCKS, batches), RTHREADS, 0, stream>>>(src, dst, partials);
    solve3x3<<<batches, RBLOCKS, 0, stream>>>(partials, (float*)coef);
    apply_map<<<dim3(RBLOCKS, batches), 256, 0, stream>>>(src, out, coef);
}